// Round 12
// baseline (888.134 us; speedup 1.0000x reference)
//
#include <hip/hip_runtime.h>
#include <math.h>

#define B_  32
#define L_  1024
#define M_  (B_*L_)      // 32768 rows
#define DM  128
#define DI  256
#define DS  16
#define DC  4
#define DR  8
#define NL  2

typedef unsigned int  uint32;
typedef unsigned short ush;
typedef __attribute__((ext_vector_type(8))) short bf16x8;
typedef __attribute__((ext_vector_type(4))) float f32x4;

__device__ __forceinline__ float silu_f(float x) { return x / (1.f + expf(-x)); }
__device__ __forceinline__ float softplus_f(float x) {
    return fmaxf(x, 0.f) + log1pf(expf(-fabsf(x)));
}
// bf16 RNE round
__device__ __forceinline__ ush f2bf(float x) {
    union { float f; uint32 u; } v; v.f = x;
    uint32 lsb = (v.u >> 16) & 1u;
    v.u += 0x7fffu + lsb;
    return (ush)(v.u >> 16);
}
__device__ __forceinline__ void split2(float x, ush& h, ush& l) {
    h = f2bf(x);
    float fh = __uint_as_float(((uint32)h) << 16);
    l = f2bf(x - fh);
}
__device__ __forceinline__ uint32 pack_pair(float x) {
    ush h, l; split2(x, h, l);
    return (uint32)h | ((uint32)l << 16);
}
__device__ __forceinline__ float unpack_pair(uint32 v) {
    return __uint_as_float(v << 16) + __uint_as_float(v & 0xffff0000u);
}

// ---------------------------------------------------------------- weight split
__global__ __launch_bounds__(256) void cvt_pair_kernel(
        const float* __restrict__ src, ush* __restrict__ h, ush* __restrict__ l, int n) {
    int i = blockIdx.x * 256 + threadIdx.x;
    if (i < n) { ush hh, ll; split2(src[i], hh, ll); h[i] = hh; l[i] = ll; }
}

// ---------------------------------------------------------------- PE table
__global__ __launch_bounds__(256) void pe_kernel(float* __restrict__ pe) {
    int idx = blockIdx.x * 256 + threadIdx.x;     // over 1024*64
    int t = idx >> 6, i = idx & 63;
    float div = expf(-0.07195578415606394f * (float)(2 * i));  // -ln(10000)/128
    float ang = (float)t * div;
    pe[t * 128 + 2 * i]     = sinf(ang);
    pe[t * 128 + 2 * i + 1] = cosf(ang);
}

// ---------------------------------------------------------------- embed
__global__ __launch_bounds__(256) void embed_kernel(
        const float* __restrict__ x_enc, const float* __restrict__ x_mark,
        const float* __restrict__ tokW, const float* __restrict__ tempW,
        const float* __restrict__ pe, float* __restrict__ out) {
    int idx = blockIdx.x * 256 + threadIdx.x;      // over M_*DM
    int d = idx & 127;
    int m = idx >> 7;
    int b = m >> 10, t = m & 1023;
    const float* xb = x_enc + (size_t)b * L_ * 7;
    float acc = pe[t * 128 + d];
    #pragma unroll
    for (int w = 0; w < 3; ++w) {
        int tt = t + w - 1;
        tt = (tt < 0) ? (L_ - 1) : (tt >= L_ ? 0 : tt);   // circular pad
        const float* xr = xb + tt * 7;
        #pragma unroll
        for (int f = 0; f < 7; ++f) acc += xr[f] * tokW[(d * 7 + f) * 3 + w];
    }
    const float* mr = x_mark + (size_t)m * 4;
    #pragma unroll
    for (int f = 0; f < 4; ++f) acc += mr[f] * tempW[d * 4 + f];
    out[idx] = acc;
}

// ---------------------------------------------------------------- layernorm (layer mode: bf16 hi/lo planes)
__global__ __launch_bounds__(256) void ln_kernel(
        const float* __restrict__ a, const float* __restrict__ b,
        const float* __restrict__ w, const float* __restrict__ bias,
        ush* __restrict__ outh, ush* __restrict__ outl,
        float* __restrict__ out_res) {
    int wv = threadIdx.x >> 6, lane = threadIdx.x & 63;
    size_t m = (size_t)blockIdx.x * 4 + wv;
    size_t base = m * DM;
    float x0 = a[base + lane], x1 = a[base + lane + 64];
    if (b) { x0 += b[base + lane]; x1 += b[base + lane + 64]; }
    out_res[base + lane] = x0; out_res[base + lane + 64] = x1;
    float s = x0 + x1;
    #pragma unroll
    for (int o = 1; o < 64; o <<= 1) s += __shfl_xor(s, o, 64);
    float mu = s * (1.f / 128.f);
    float d0 = x0 - mu, d1 = x1 - mu;
    float v = d0 * d0 + d1 * d1;
    #pragma unroll
    for (int o = 1; o < 64; o <<= 1) v += __shfl_xor(v, o, 64);
    float inv = rsqrtf(v * (1.f / 128.f) + 1e-5f);
    float r0 = d0 * inv * w[lane]      + bias[lane];
    float r1 = d1 * inv * w[lane + 64] + bias[lane + 64];
    ush h, l;
    split2(r0, h, l); outh[base + lane] = h;      outl[base + lane] = l;
    split2(r1, h, l); outh[base + lane + 64] = h; outl[base + lane + 64] = l;
}

// ---------------------------------------------------------------- final LN + out-projection (fused)
__global__ __launch_bounds__(256) void ln_out_kernel(
        const float* __restrict__ a, const float* __restrict__ b,
        const float* __restrict__ w, const float* __restrict__ bias,
        const float* __restrict__ finW, float* __restrict__ out) {
    int wv = threadIdx.x >> 6, lane = threadIdx.x & 63;
    size_t m = (size_t)blockIdx.x * 4 + wv;
    size_t base = m * DM;
    float x0 = a[base + lane] + b[base + lane];
    float x1 = a[base + lane + 64] + b[base + lane + 64];
    float s = x0 + x1;
    #pragma unroll
    for (int o = 1; o < 64; o <<= 1) s += __shfl_xor(s, o, 64);
    float mu = s * (1.f / 128.f);
    float d0 = x0 - mu, d1 = x1 - mu;
    float v = d0 * d0 + d1 * d1;
    #pragma unroll
    for (int o = 1; o < 64; o <<= 1) v += __shfl_xor(v, o, 64);
    float inv = rsqrtf(v * (1.f / 128.f) + 1e-5f);
    float r0 = d0 * inv * w[lane]      + bias[lane];
    float r1 = d1 * inv * w[lane + 64] + bias[lane + 64];
    #pragma unroll
    for (int c = 0; c < 7; ++c) {
        float p = r0 * finW[c * 128 + lane] + r1 * finW[c * 128 + lane + 64];
        #pragma unroll
        for (int o = 1; o < 64; o <<= 1) p += __shfl_xor(p, o, 64);
        if (lane == 0) out[m * 7 + c] = p;
    }
}

// ---------------------------------------------------------------- in_proj MFMA (split-bf16, no LDS)
__global__ __launch_bounds__(256) void gemm_inproj_mfma(
        const ush* __restrict__ Ah, const ush* __restrict__ Al,
        const ush* __restrict__ Wh, const ush* __restrict__ Wl,
        float* __restrict__ xiT, float* __restrict__ zsilT) {
    int bm = blockIdx.y * 128, bn = blockIdx.x * 128;
    int w = threadIdx.x >> 6, l = threadIdx.x & 63;
    int lm = l & 15, lk8 = (l >> 4) * 8;
    f32x4 acc[2][8];
    #pragma unroll
    for (int mi = 0; mi < 2; ++mi)
        #pragma unroll
        for (int ni = 0; ni < 8; ++ni) acc[mi][ni] = {0.f, 0.f, 0.f, 0.f};
    const ush* ah = Ah + (size_t)(bm + w * 32 + lm) * 128;
    const ush* al = Al + (size_t)(bm + w * 32 + lm) * 128;
    const ush* wh = Wh + (size_t)(bn + lm) * 128;
    const ush* wl = Wl + (size_t)(bn + lm) * 128;
    for (int k0 = 0; k0 < 128; k0 += 32) {
        bf16x8 aH[2], aL[2];
        #pragma unroll
        for (int mi = 0; mi < 2; ++mi) {
            aH[mi] = *(const bf16x8*)(ah + mi * 16 * 128 + k0 + lk8);
            aL[mi] = *(const bf16x8*)(al + mi * 16 * 128 + k0 + lk8);
        }
        #pragma unroll
        for (int ni = 0; ni < 8; ++ni) {
            bf16x8 wH = *(const bf16x8*)(wh + ni * 16 * 128 + k0 + lk8);
            bf16x8 wLo = *(const bf16x8*)(wl + ni * 16 * 128 + k0 + lk8);
            #pragma unroll
            for (int mi = 0; mi < 2; ++mi) {
                acc[mi][ni] = __builtin_amdgcn_mfma_f32_16x16x32_bf16(aL[mi], wH,  acc[mi][ni], 0, 0, 0);
                acc[mi][ni] = __builtin_amdgcn_mfma_f32_16x16x32_bf16(aH[mi], wLo, acc[mi][ni], 0, 0, 0);
                acc[mi][ni] = __builtin_amdgcn_mfma_f32_16x16x32_bf16(aH[mi], wH,  acc[mi][ni], 0, 0, 0);
            }
        }
    }
    int b = bm >> 10;
    int tl0 = (bm & 1023) + w * 32 + (l >> 4) * 4;
    #pragma unroll
    for (int ni = 0; ni < 8; ++ni) {
        int n = bn + ni * 16 + lm;
        #pragma unroll
        for (int mi = 0; mi < 2; ++mi) {
            int tl = tl0 + mi * 16;
            f32x4 v = acc[mi][ni];
            if (bn < 256) {
                *(f32x4*)(xiT + ((size_t)(b * 256 + n)) * 1024 + tl) = v;
            } else {
                f32x4 r;
                #pragma unroll
                for (int i = 0; i < 4; ++i) r[i] = silu_f(v[i]);
                *(f32x4*)(zsilT + ((size_t)(b * 256 + n - 256)) * 1024 + tl) = r;
            }
        }
    }
}

// ---------------------------------------------------------------- A-transposed MFMA GEMM (split-bf16)
template<int NF, int KTOT>
__global__ __launch_bounds__(256) void gemm_at_mfma(
        const uint32* __restrict__ A32, const ush* __restrict__ Wh,
        const ush* __restrict__ Wl, int Nvalid,
        float* __restrict__ Cnm, float* __restrict__ Cmn) {
    __shared__ uint32 As[128][68];   // BK=64 interleaved hi|lo
    int bm = blockIdx.x * 128;
    int b = bm >> 10, tloc = bm & 1023;
    int tid = threadIdx.x;
    int w = tid >> 6, l = tid & 63;
    int lm = l & 15, lk8 = (l >> 4) * 8;
    f32x4 acc[2][NF];
    #pragma unroll
    for (int mi = 0; mi < 2; ++mi)
        #pragma unroll
        for (int ni = 0; ni < NF; ++ni) acc[mi][ni] = {0.f, 0.f, 0.f, 0.f};

    for (int k0 = 0; k0 < KTOT; k0 += 64) {
        __syncthreads();
        {   // stage + transpose: [64 k][128 m] -> As[m][k]
            int k = tid >> 2, mq = tid & 3;
            const uint32* src = A32 + ((size_t)(b * KTOT + k0 + k)) * 1024 + tloc + mq * 32;
            #pragma unroll
            for (int c = 0; c < 8; ++c) {
                uint4 v = *(const uint4*)(src + c * 4);
                As[mq * 32 + c * 4 + 0][k] = v.x;
                As[mq * 32 + c * 4 + 1][k] = v.y;
                As[mq * 32 + c * 4 + 2][k] = v.z;
                As[mq * 32 + c * 4 + 3][k] = v.w;
            }
        }
        __syncthreads();
        #pragma unroll
        for (int ks = 0; ks < 2; ++ks) {
            int kk = ks * 32 + lk8;
            bf16x8 aH[2], aL[2];
            #pragma unroll
            for (int mi = 0; mi < 2; ++mi) {
                int m = w * 32 + mi * 16 + lm;
                uint4 p0 = *(const uint4*)&As[m][kk];
                uint4 p1 = *(const uint4*)&As[m][kk + 4];
                uint32 u[8] = {p0.x, p0.y, p0.z, p0.w, p1.x, p1.y, p1.z, p1.w};
                bf16x8 h, lo;
                #pragma unroll
                for (int j = 0; j < 8; ++j) {
                    h[j]  = (short)(u[j] & 0xffffu);
                    lo[j] = (short)(u[j] >> 16);
                }
                aH[mi] = h; aL[mi] = lo;
            }
            #pragma unroll
            for (int ni = 0; ni < NF; ++ni) {
                int n = ni * 16 + lm;
                bf16x8 wH = {0,0,0,0,0,0,0,0}, wLo = {0,0,0,0,0,0,0,0};
                if (n < Nvalid) {
                    wH  = *(const bf16x8*)(Wh + (size_t)n * KTOT + k0 + ks * 32 + lk8);
                    wLo = *(const bf16x8*)(Wl + (size_t)n * KTOT + k0 + ks * 32 + lk8);
                }
                #pragma unroll
                for (int mi = 0; mi < 2; ++mi) {
                    acc[mi][ni] = __builtin_amdgcn_mfma_f32_16x16x32_bf16(aL[mi], wH,  acc[mi][ni], 0, 0, 0);
                    acc[mi][ni] = __builtin_amdgcn_mfma_f32_16x16x32_bf16(aH[mi], wLo, acc[mi][ni], 0, 0, 0);
                    acc[mi][ni] = __builtin_amdgcn_mfma_f32_16x16x32_bf16(aH[mi], wH,  acc[mi][ni], 0, 0, 0);
                }
            }
        }
    }
    int m0 = w * 32 + (l >> 4) * 4;
    #pragma unroll
    for (int ni = 0; ni < NF; ++ni) {
        int n = ni * 16 + lm;
        #pragma unroll
        for (int mi = 0; mi < 2; ++mi) {
            f32x4 v = acc[mi][ni];
            int mg = bm + m0 + mi * 16;
            if (Cnm) {
                if (n < Nvalid) *(f32x4*)(Cnm + (size_t)n * M_ + mg) = v;
            } else {
                #pragma unroll
                for (int r = 0; r < 4; ++r)
                    Cmn[(size_t)(mg + r) * Nvalid + n] = v[r];
            }
        }
    }
}

// ---------------------------------------------------------------- conv + silu -> packed uT32
__global__ __launch_bounds__(256) void conv_T_kernel(
        const float* __restrict__ xiT, const float* __restrict__ cw,
        const float* __restrict__ cb, uint32* __restrict__ uT32) {
    int wv = threadIdx.x >> 6, lane = threadIdx.x & 63;
    int rid = blockIdx.x * 4 + wv;            // b*256 + d
    int d = rid & 255;
    const float* src = xiT + (size_t)rid * 1024;
    int t0 = lane * 16;
    float x[20];
    {
        float4 p = (lane > 0) ? *(const float4*)(src + t0 - 4)
                              : make_float4(0.f, 0.f, 0.f, 0.f);
        *(float4*)&x[0] = p;
        #pragma unroll
        for (int c = 0; c < 4; ++c)
            *(float4*)&x[4 + c * 4] = *(const float4*)(src + t0 + c * 4);
    }
    float4 w4 = ((const float4*)cw)[d];
    float bias = cb[d];
    uint32* dst = uT32 + (size_t)rid * 1024 + t0;
    #pragma unroll
    for (int c = 0; c < 4; ++c) {
        uint4 o;
        uint32 ov[4];
        #pragma unroll
        for (int i = 0; i < 4; ++i) {
            int k = c * 4 + i;
            float acc = bias + x[k + 1] * w4.x + x[k + 2] * w4.y
                             + x[k + 3] * w4.z + x[k + 4] * w4.w;
            ov[i] = pack_pair(silu_f(acc));
        }
        o.x = ov[0]; o.y = ov[1]; o.z = ov[2]; o.w = ov[3];
        *(uint4*)(dst + c * 4) = o;
    }
}

// ---------------------------------------------------------------- dtT from dbcT (broadcast loads) — round-7 proven version
__global__ __launch_bounds__(256) void dtT_kernel(
        const float* __restrict__ dbcT, const float* __restrict__ dtW,
        const float* __restrict__ dtb, float* __restrict__ dtT) {
    int n = threadIdx.x;
    int m0 = blockIdx.x * 64;
    int b = m0 >> 10, t0 = m0 & 1023;
    float wk[8];
    *(float4*)&wk[0] = ((const float4*)dtW)[n * 2];
    *(float4*)&wk[4] = ((const float4*)dtW)[n * 2 + 1];
    float bias = dtb[n];
    float* dst = dtT + ((size_t)(b * 256 + n)) * 1024 + t0;
    for (int r4 = 0; r4 < 64; r4 += 4) {
        float col[8][4];
        #pragma unroll
        for (int k = 0; k < 8; ++k)
            *(float4*)col[k] = *(const float4*)(dbcT + (size_t)k * M_ + m0 + r4);
        float o[4];
        #pragma unroll
        for (int i = 0; i < 4; ++i) {
            float a = bias;
            #pragma unroll
            for (int k = 0; k < 8; ++k) a += col[k][i] * wk[k];
            o[i] = softplus_f(a);
        }
        *(float4*)(dst + r4) = make_float4(o[0], o[1], o[2], o[3]);
    }
}

// ---------------------------------------------------------------- scan v7: two-level (2 waves/row), prefetched B/C
// block = 256 thr = 4 waves = 2 rows x 2 halves; lane owns 8 t.
// Per s-pair: both halves do local+KS in parallel; wave A publishes its end
// state via LDS; wave B folds it into its carry. 1 barrier per pair.
__global__ __launch_bounds__(256) void scan7_kernel(
        const float* __restrict__ dtT, const uint32* __restrict__ uT32,
        const float* __restrict__ dbcT, const float* __restrict__ A_log,
        const float* __restrict__ zsilT, const float* __restrict__ Dp,
        uint32* __restrict__ yT32) {
    __shared__ float sh[2][2][2];     // [pair parity][row_local][state]
    int w = threadIdx.x >> 6, lane = threadIdx.x & 63;
    int half = w & 1, rl = w >> 1;
    int wid = blockIdx.x * 2 + rl;    // b*256 + d
    int b = wid >> 8, d = wid & 255;
    size_t base = (size_t)wid * 1024 + half * 512 + (size_t)lane * 8;
    size_t mrow = (size_t)b * 1024 + half * 512 + (size_t)lane * 8;

    float dt[8], du[8], y[8], pcA[8], pcB[8];
    {
        const float4* p = (const float4*)(dtT + base);
        const uint4*  q = (const uint4*)(uT32 + base);
        #pragma unroll
        for (int c = 0; c < 2; ++c) {
            float4 dv = p[c]; uint4 uv = q[c];
            dt[c * 4 + 0] = dv.x; dt[c * 4 + 1] = dv.y; dt[c * 4 + 2] = dv.z; dt[c * 4 + 3] = dv.w;
            du[c * 4 + 0] = dv.x * unpack_pair(uv.x);
            du[c * 4 + 1] = dv.y * unpack_pair(uv.y);
            du[c * 4 + 2] = dv.z * unpack_pair(uv.z);
            du[c * 4 + 3] = dv.w * unpack_pair(uv.w);
        }
        #pragma unroll
        for (int i = 0; i < 8; ++i) y[i] = 0.f;
    }
    const float* Bb = dbcT + (size_t)8  * M_ + mrow;
    const float* Cb = dbcT + (size_t)24 * M_ + mrow;
    const float* Arow = A_log + d * 16;

    // prefetch pair 0
    float4 nB0[2], nB1[2], nC0[2], nC1[2];
    #pragma unroll
    for (int c = 0; c < 2; ++c) {
        nB0[c] = *(const float4*)(Bb + c * 4);
        nB1[c] = *(const float4*)(Bb + (size_t)M_ + c * 4);
        nC0[c] = *(const float4*)(Cb + c * 4);
        nC1[c] = *(const float4*)(Cb + (size_t)M_ + c * 4);
    }

    #pragma unroll
    for (int p = 0; p < 8; ++p) {
        float4 B0[2], B1[2], C0[2], C1[2];
        #pragma unroll
        for (int c = 0; c < 2; ++c) { B0[c] = nB0[c]; B1[c] = nB1[c]; C0[c] = nC0[c]; C1[c] = nC1[c]; }
        if (p < 7) {    // issue next pair's loads before the compute chain
            size_t s0 = (size_t)(2 * p + 2) * M_, s1 = (size_t)(2 * p + 3) * M_;
            #pragma unroll
            for (int c = 0; c < 2; ++c) {
                nB0[c] = *(const float4*)(Bb + s0 + c * 4);
                nB1[c] = *(const float4*)(Bb + s1 + c * 4);
                nC0[c] = *(const float4*)(Cb + s0 + c * 4);
                nC1[c] = *(const float4*)(Cb + s1 + c * 4);
            }
        }
        float A2a = -expf(Arow[2 * p])     * 1.4426950408889634f;
        float A2b = -expf(Arow[2 * p + 1]) * 1.4426950408889634f;
        float h0 = 0.f, P0 = 1.f, h1 = 0.f, P1 = 1.f;
        #pragma unroll
        for (int c = 0; c < 2; ++c) {
            float Bv0[4] = {B0[c].x, B0[c].y, B0[c].z, B0[c].w};
            float Cv0[4] = {C0[c].x, C0[c].y, C0[c].z, C0[c].w};
            float Bv1[4] = {B1[c].x, B1[c].y, B1[c].z, B1[c].w};
            float Cv1[4] = {C1[c].x, C1[c].y, C1[c].z, C1[c].w};
            #pragma unroll
            for (int i = 0; i < 4; ++i) {
                int ii = c * 4 + i;
                float a0 = __builtin_amdgcn_exp2f(dt[ii] * A2a);
                float a1 = __builtin_amdgcn_exp2f(dt[ii] * A2b);
                h0 = a0 * h0 + du[ii] * Bv0[i];  P0 *= a0;
                h1 = a1 * h1 + du[ii] * Bv1[i];  P1 *= a1;
                y[ii] += h0 * Cv0[i] + h1 * Cv1[i];
                pcA[ii] = P0 * Cv0[i];
                pcB[ii] = P1 * Cv1[i];
            }
        }
        // dual Kogge-Stone over 64 lanes
        float Aag0 = P0, E0 = h0, Aag1 = P1, E1 = h1;
        #pragma unroll
        for (int dlt = 1; dlt < 64; dlt <<= 1) {
            float Au0 = __shfl_up(Aag0, dlt, 64), Eu0 = __shfl_up(E0, dlt, 64);
            float Au1 = __shfl_up(Aag1, dlt, 64), Eu1 = __shfl_up(E1, dlt, 64);
            if (lane >= dlt) {
                E0 = Aag0 * Eu0 + E0;  Aag0 *= Au0;
                E1 = Aag1 * Eu1 + E1;  Aag1 *= Au1;
            }
        }
        // cross-wave carry: wave A publishes end state; wave B folds it in
        if (half == 0 && lane == 63) { sh[p & 1][rl][0] = E0; sh[p & 1][rl][1] = E1; }
        __syncthreads();
        float SA0 = half ? sh[p & 1][rl][0] : 0.f;
        float SA1 = half ? sh[p & 1][rl][1] : 0.f;
        float Eu0 = __shfl_up(E0, 1, 64), Au0 = __shfl_up(Aag0, 1, 64);
        float Eu1 = __shfl_up(E1, 1, 64), Au1 = __shfl_up(Aag1, 1, 64);
        if (lane == 0) { Eu0 = 0.f; Au0 = 1.f; Eu1 = 0.f; Au1 = 1.f; }
        float car0 = Eu0 + Au0 * SA0;
        float car1 = Eu1 + Au1 * SA1;
        #pragma unroll
        for (int i = 0; i < 8; ++i) y[i] += car0 * pcA[i] + car1 * pcB[i];
    }

    // epilogue: u = du/dt (guarded); gate with u*D and pre-silu'd z
    float Dv = Dp[d];
    const float4* qz = (const float4*)(zsilT + base);
    uint32* dst = yT32 + base;
    #pragma unroll
    for (int c = 0; c < 2; ++c) {
        float4 zv = qz[c];
        float za[4] = {zv.x, zv.y, zv.z, zv.w};
        uint32 ov[4];
        #pragma unroll
        for (int i = 0; i < 4; ++i) {
            int ii = c * 4 + i;
            float u = (dt[ii] > 0.f) ? du[ii] * __builtin_amdgcn_rcpf(dt[ii]) : 0.f;
            ov[i] = pack_pair((y[ii] + u * Dv) * za[i]);
        }
        uint4 o; o.x = ov[0]; o.y = ov[1]; o.z = ov[2]; o.w = ov[3];
        *(uint4*)(dst + c * 4) = o;
    }
}

// ================================================================ launch
extern "C" void kernel_launch(void* const* d_in, const int* in_sizes, int n_in,
                              void* d_out, int out_size, void* d_ws, size_t ws_size,
                              hipStream_t stream) {
    const float* x_enc  = (const float*)d_in[0];
    const float* x_mark = (const float*)d_in[1];
    const float* tokW   = (const float*)d_in[4];
    const float* tempW  = (const float*)d_in[5];
    const float* norm_w = (const float*)d_in[6];
    const float* norm_b = (const float*)d_in[7];
    const float* inW    = (const float*)d_in[8];
    const float* convW  = (const float*)d_in[9];
    const float* convB  = (const float*)d_in[10];
    const float* xpW    = (const float*)d_in[11];
    const float* dtW    = (const float*)d_in[12];
    const float* dtbp   = (const float*)d_in[13];
    const float* A_log  = (const float*)d_in[14];
    const float* Dp     = (const float*)d_in[15];
    const float* outW   = (const float*)d_in[16];
    const float* nfw    = (const float*)d_in[17];
    const float* nfb    = (const float*)d_in[18];
    const float* finW   = (const float*)d_in[19];
    float* out = (float*)d_out;

    float* ws = (float*)d_ws;
    size_t o = 0;
    float*  hidden   = ws + o; o += (size_t)M_ * DM;
    float*  residual = ws + o; o += (size_t)M_ * DM;
    float*  xlnP     = ws + o; o += (size_t)M_ * DM;   // hosts bf16 hi/lo planes
    float*  xiT      = ws + o; o += (size_t)M_ * DI;
    float*  zsilT    = ws + o; o += (size_t)M_ * DI;
    uint32* uT32     = (uint32*)(ws + o); o += (size_t)M_ * DI;
    float*  dbcT     = ws + o; o += (size_t)M_ * 40;   // [40][M]; pe aliases front
    float*  dtT      = ws + o; o += (size_t)M_ * DI;
    uint32* yT32     = (uint32*)(ws + o); o += (size_t)M_ * DI;
    ush* inWh  = (ush*)(ws + o); o += (size_t)NL * 512 * DM / 2;
    ush* inWl  = (ush*)(ws + o); o += (size_t)NL * 512 * DM / 2;
    ush* xpWh  = (ush*)(ws + o); o += (size_t)NL * 40 * DI / 2;
    ush* xpWl  = (ush*)(ws + o); o += (size_t)NL * 40 * DI / 2;
    ush* outWh = (ush*)(ws + o); o += (size_t)NL * DM * DI / 2;
    ush* outWl = (ush*)(ws + o); o += (size_t)NL * DM * DI / 2;
    ush* xlnh = (ush*)xlnP;
    ush* xlnl = xlnh + (size_t)M_ * DM;
    float* pe = dbcT;                          // pe dead before dbcT written

    dim3 blk(256);
    pe_kernel<<<1024 * 64 / 256, blk, 0, stream>>>(pe);
    embed_kernel<<<M_ * DM / 256, blk, 0, stream>>>(x_enc, x_mark, tokW, tempW, pe, hidden);
    {
        int n1 = NL * 512 * DM, n2 = NL * 40 * DI, n3 = NL * DM * DI;
        cvt_pair_kernel<<<(n1 + 255) / 256, blk, 0, stream>>>(inW,  inWh,  inWl,  n1);
        cvt_pair_kernel<<<(n2 + 255) / 256, blk, 0, stream>>>(xpW,  xpWh,  xpWl,  n2);
        cvt_pair_kernel<<<(n3 + 255) / 256, blk, 0, stream>>>(outW, outWh, outWl, n3);
    }

    for (int l = 0; l < NL; ++l) {
        ln_kernel<<<M_ / 4, blk, 0, stream>>>(hidden, l ? residual : nullptr,
                                              norm_w + l * DM, norm_b + l * DM,
                                              xlnh, xlnl, residual);
        gemm_inproj_mfma<<<dim3(4, M_ / 128), blk, 0, stream>>>(
            xlnh, xlnl, inWh + (size_t)l * 512 * DM, inWl + (size_t)l * 512 * DM,
            xiT, zsilT);
        conv_T_kernel<<<B_ * DI / 4, blk, 0, stream>>>(xiT, convW + l * DI * DC,
                                                       convB + l * DI, uT32);
        gemm_at_mfma<3, 256><<<M_ / 128, blk, 0, stream>>>(
            uT32, xpWh + (size_t)l * 40 * DI, xpWl + (size_t)l * 40 * DI,
            40, dbcT, nullptr);
        dtT_kernel<<<M_ / 64, blk, 0, stream>>>(dbcT, dtW + l * DI * DR,
                                                dtbp + l * DI, dtT);
        scan7_kernel<<<B_ * DI / 2, blk, 0, stream>>>(dtT, uT32, dbcT,
                                                      A_log + l * DI * DS, zsilT,
                                                      Dp + l * DI, yT32);
        gemm_at_mfma<8, 256><<<M_ / 128, blk, 0, stream>>>(
            yT32, outWh + (size_t)l * DM * DI, outWl + (size_t)l * DM * DI,
            128, nullptr, hidden);
    }

    ln_out_kernel<<<M_ / 4, blk, 0, stream>>>(hidden, residual, nfw, nfb, finW, out);
}